// Round 12
// baseline (105.168 us; speedup 1.0000x reference)
//
#include <hip/hip_runtime.h>
#include <cstdint>

#define B_ 32
#define P_ 65536
#define O_ 32
#define GX_ 64            // main grid.x; 1024 priors per block
#define KC_ 4             // priors per thread
#define NCELL_ 16
#define NC_ (NCELL_ * NCELL_)
#define HB_ 32            // histogram/scatter blocks
#define PPH_ (P_ / (HB_ * 256))   // 8 priors per thread in hist/scatter
#define MARGIN_ 0.1501f   // max prior half-extent (wh<=0.3) + slack
#define THRESH_ 0.35f
#define VAR0 0.1f
#define VAR1 0.2f
#define EPS_ 1e-7f
#define ALPHA_ 0.25f

struct WSHdr {
  unsigned long long gkey[B_ * O_];  // per (b,o): (iou_bits<<32)|(~p)
  float4 part[GX_ * B_];             // per-block partials (ll, lc, llm, n1)
  double corr[B_][4];                // per-batch forced-match corrections
  unsigned blkcnt[HB_ * NC_];
  unsigned blkbase[HB_ * NC_];
  unsigned idx_sorted[P_];           // slot -> orig p
  unsigned sortrank[P_];             // orig p -> slot
  float4 priors_sorted[P_];
};
// After WSHdr: unsigned pb32[B_*P_]  ((iou_bits&~0x3F)|bidx), indexed by slot.
// The first 256KB of that region doubles as cellid[P_] (dead before pb32 use).

__device__ __forceinline__ float frcp(float x) { return __builtin_amdgcn_rcpf(x); }

template <int CTRL>
__device__ __forceinline__ float dpp_fmax(float v) {
  int s = __builtin_amdgcn_update_dpp(0, __float_as_int(v), CTRL, 0xF, 0xF, true);
  return fmaxf(v, __int_as_float(s));
}
template <int CTRL>
__device__ __forceinline__ unsigned dpp_umax(unsigned v) {
  unsigned u = (unsigned)__builtin_amdgcn_update_dpp(0, (int)v, CTRL, 0xF, 0xF, true);
  return u > v ? u : v;
}

// ---- shared loss math (identical expressions everywhere) --------------------
__device__ __forceinline__ float focal_term(float2 cf, bool pos) {
  float mx = fmaxf(cf.x, cf.y);
  float lse = mx + __logf(1.f + __expf(-fabsf(cf.x - cf.y)));
  float logpt = (pos ? cf.y : cf.x) - lse;
  float pt = __expf(logpt);
  float om = 1.f - pt;
  return -ALPHA_ * om * sqrtf(om) * logpt;
}

__device__ __forceinline__ float giou_term(float4 pr, float4 loc,
                                           float b2x1, float b2y1,
                                           float b2x2, float b2y2) {
  float dx = pr.x + loc.x * VAR0 * pr.z;
  float dy = pr.y + loc.y * VAR0 * pr.w;
  float dw = pr.z * __expf(loc.z * VAR1);
  float dh = pr.w * __expf(loc.w * VAR1);
  float b1x1 = dx - dw * 0.5f, b1y1 = dy - dh * 0.5f;
  float b1x2 = dx + dw * 0.5f, b1y2 = dy + dh * 0.5f;
  float a1 = (b1x2 - b1x1) * (b1y2 - b1y1);
  float a2 = (b2x2 - b2x1) * (b2y2 - b2y1);
  float iw = fmaxf(fminf(b1x2, b2x2) - fmaxf(b1x1, b2x1), 0.f);
  float ih = fmaxf(fminf(b1y2, b2y2) - fmaxf(b1y1, b2y1), 0.f);
  float inter = iw * ih;
  float uni = a1 + a2 - inter;
  float iou = inter * frcp(uni + EPS_);
  float ew = fmaxf(b1x2, b2x2) - fminf(b1x1, b2x1);
  float eh = fmaxf(b1y2, b2y2) - fminf(b1y1, b2y1);
  float enc = ew * eh;
  float g = iou - (enc - uni) * frcp(enc + EPS_);
  return 1.f - g;
}

__device__ __forceinline__ float landm_term(float4 pr,
                                            const float* __restrict__ lmrow,
                                            const float* __restrict__ tlm_row) {
  float rw = frcp(VAR0 * pr.z);
  float rh = frcp(VAR0 * pr.w);
  float llm = 0.f;
  #pragma unroll
  for (int q = 0; q < 5; ++q) {
    float2 d = *reinterpret_cast<const float2*>(lmrow + q * 2);
    float ex = d.x - (tlm_row[2 * q] - pr.x) * rw;
    float ey = d.y - (tlm_row[2 * q + 1] - pr.y) * rh;
    float ax = fabsf(ex), ay = fabsf(ey);
    llm += (ax < 1.f) ? 0.5f * ex * ex : ax - 0.5f;
    llm += (ay < 1.f) ? 0.5f * ey * ey : ay - 0.5f;
  }
  return llm;
}

// ===================== sort prep (batch-independent) ========================

__global__ __launch_bounds__(256) void k_hist(const float* __restrict__ priors,
                                              WSHdr* __restrict__ ws,
                                              unsigned* __restrict__ cellid) {
  __shared__ unsigned lh[NC_];
  const int tid = threadIdx.x;
  lh[tid] = 0u;
  if (blockIdx.x == 0) {          // fold gkey seed into first hist block
    for (int i = tid; i < B_ * O_; i += 256) ws->gkey[i] = 0xFFFFFFFFull;
  }
  __syncthreads();
  const int pb0 = blockIdx.x * (256 * PPH_);
  #pragma unroll
  for (int i = 0; i < PPH_; ++i) {
    const int p = pb0 + i * 256 + tid;
    float4 pr = reinterpret_cast<const float4*>(priors)[p];
    int cx = min(NCELL_ - 1, max(0, (int)(pr.x * (float)NCELL_)));
    int cy = min(NCELL_ - 1, max(0, (int)(pr.y * (float)NCELL_)));
    unsigned c = (unsigned)(cy * NCELL_ + cx);
    cellid[p] = c;
    atomicAdd(&lh[c], 1u);
  }
  __syncthreads();
  ws->blkcnt[blockIdx.x * NC_ + tid] = lh[tid];
}

__global__ __launch_bounds__(256) void k_scan2(WSHdr* ws) {
  __shared__ unsigned s[NC_];
  const int c = threadIdx.x;
  unsigned tot = 0;
  for (int blk = 0; blk < HB_; ++blk) tot += ws->blkcnt[blk * NC_ + c];
  s[c] = tot;
  __syncthreads();
  for (int off = 1; off < NC_; off <<= 1) {
    unsigned t = (c >= off) ? s[c - off] : 0u;
    __syncthreads();
    s[c] += t;
    __syncthreads();
  }
  unsigned run = s[c] - tot;   // exclusive cell base
  for (int blk = 0; blk < HB_; ++blk) {
    ws->blkbase[blk * NC_ + c] = run;
    run += ws->blkcnt[blk * NC_ + c];
  }
}

__global__ __launch_bounds__(256) void k_scatter2(const float* __restrict__ priors,
                                                  WSHdr* __restrict__ ws,
                                                  const unsigned* __restrict__ cellid) {
  __shared__ unsigned lcur[NC_];
  const int tid = threadIdx.x;
  lcur[tid] = ws->blkbase[blockIdx.x * NC_ + tid];
  __syncthreads();
  const int pb0 = blockIdx.x * (256 * PPH_);
  #pragma unroll
  for (int i = 0; i < PPH_; ++i) {
    const int p = pb0 + i * 256 + tid;
    unsigned c = cellid[p];
    unsigned slot = atomicAdd(&lcur[c], 1u);
    ws->idx_sorted[slot] = (unsigned)p;
    ws->sortrank[p] = slot;
    ws->priors_sorted[slot] = reinterpret_cast<const float4*>(priors)[p];
  }
}

// ===================== match (sorted order, culled) =========================
__global__ __launch_bounds__(256) void k_match2(const float* __restrict__ targets,
                                                WSHdr* __restrict__ ws,
                                                unsigned* __restrict__ pb32) {
  __shared__ unsigned long long kq[O_][17];
  const int b = blockIdx.y;
  const int tid = threadIdx.x;
  const int lane = tid & 63, wid = tid >> 6;
  for (int i = tid; i < O_ * 17; i += 256) ((unsigned long long*)kq)[i] = 0ull;

  const int slot0 = blockIdx.x * 1024 + tid * KC_;
  float px1[KC_], py1[KC_], px2[KC_], py2[KC_], pa[KC_], bov[KC_];
  int bidx[KC_];
  unsigned pinv[KC_];
  uint4 opv = *reinterpret_cast<const uint4*>(&ws->idx_sorted[slot0]);
  pinv[0] = 0xFFFFFFFFu - opv.x; pinv[1] = 0xFFFFFFFFu - opv.y;
  pinv[2] = 0xFFFFFFFFu - opv.z; pinv[3] = 0xFFFFFFFFu - opv.w;
  float mnx = 1e9f, mxx = -1e9f, mny = 1e9f, mxy = -1e9f;
  #pragma unroll
  for (int k = 0; k < KC_; ++k) {
    float4 pr = ws->priors_sorted[slot0 + k];
    px1[k] = pr.x - pr.z * 0.5f; py1[k] = pr.y - pr.w * 0.5f;
    px2[k] = pr.x + pr.z * 0.5f; py2[k] = pr.y + pr.w * 0.5f;
    pa[k] = (px2[k] - px1[k]) * (py2[k] - py1[k]);
    bov[k] = 0.f; bidx[k] = 0;
    mnx = fminf(mnx, pr.x); mxx = fmaxf(mxx, pr.x);
    mny = fminf(mny, pr.y); mxy = fmaxf(mxy, pr.y);
  }
  #pragma unroll
  for (int i = 1; i < 64; i <<= 1) {
    mnx = fminf(mnx, __shfl_xor(mnx, i));
    mxx = fmaxf(mxx, __shfl_xor(mxx, i));
    mny = fminf(mny, __shfl_xor(mny, i));
    mxy = fmaxf(mxy, __shfl_xor(mxy, i));
  }
  __syncthreads();   // kq init visible

  const float* __restrict__ tb = targets + (size_t)b * O_ * 15;
  for (int o = 0; o < O_; ++o) {
    const float x1 = tb[o * 15 + 0], y1 = tb[o * 15 + 1];
    const float x2 = tb[o * 15 + 2], y2 = tb[o * 15 + 3];
    bool hit = (x1 - MARGIN_ <= mxx) && (x2 + MARGIN_ >= mnx) &&
               (y1 - MARGIN_ <= mxy) && (y2 + MARGIN_ >= mny);
    if (hit) {
      const float ta = (x2 - x1) * (y2 - y1);
      float tiou = 0.f;
      unsigned tinv = 0u;
      #pragma unroll
      for (int k = 0; k < KC_; ++k) {
        float iw = fmaxf(fminf(x2, px2[k]) - fmaxf(x1, px1[k]), 0.f);
        float ih = fmaxf(fminf(y2, py2[k]) - fmaxf(y1, py1[k]), 0.f);
        float inter = iw * ih;
        float iou = inter * frcp(ta + pa[k] - inter);
        if (iou > bov[k]) { bov[k] = iou; bidx[k] = o; }      // o ascending
        if (iou > tiou || (iou == tiou && pinv[k] > tinv)) {  // min-p tie
          tiou = iou; tinv = pinv[k];
        }
      }
      float m = tiou;
      m = dpp_fmax<0x128>(m);
      m = dpp_fmax<0x124>(m);
      m = dpp_fmax<0x122>(m);
      m = dpp_fmax<0x121>(m);
      unsigned cand = (tiou == m) ? tinv : 0u;
      cand = dpp_umax<0x128>(cand);
      cand = dpp_umax<0x124>(cand);
      cand = dpp_umax<0x122>(cand);
      cand = dpp_umax<0x121>(cand);
      if ((lane & 15) == 0)
        kq[o][wid * 4 + (lane >> 4)] =
            ((unsigned long long)__float_as_uint(m) << 32) |
            (unsigned long long)cand;
    }
  }

  // coalesced pb32 store (uint4 per thread)
  uint4 outv;
  outv.x = (__float_as_uint(bov[0]) & 0xFFFFFFC0u) | (unsigned)bidx[0];
  outv.y = (__float_as_uint(bov[1]) & 0xFFFFFFC0u) | (unsigned)bidx[1];
  outv.z = (__float_as_uint(bov[2]) & 0xFFFFFFC0u) | (unsigned)bidx[2];
  outv.w = (__float_as_uint(bov[3]) & 0xFFFFFFC0u) | (unsigned)bidx[3];
  *reinterpret_cast<uint4*>(&pb32[(size_t)b * P_ + slot0]) = outv;

  __syncthreads();
  if (tid < O_) {
    unsigned long long best = kq[tid][0];
    #pragma unroll
    for (int s = 1; s < 16; ++s) {
      unsigned long long v = kq[tid][s];
      if (v > best) best = v;
    }
    atomicMax(&ws->gkey[(size_t)b * O_ + tid], best);
  }
}

// ===================== losses (original order, coalesced) ===================
__global__ __launch_bounds__(256) void k_loss3(const float* __restrict__ loc_data,
                                               const float* __restrict__ conf_data,
                                               const float* __restrict__ landm_data,
                                               const float* __restrict__ priors,
                                               const float* __restrict__ targets,
                                               WSHdr* __restrict__ ws,
                                               const unsigned* __restrict__ pb32) {
  __shared__ float tx1[O_], ty1[O_], tx2[O_], ty2[O_], tlbl[O_];
  __shared__ float tlm[O_][10];
  __shared__ float4 wsum[4];
  const int b = blockIdx.y;
  const int tid = threadIdx.x;
  if (tid < O_) {
    const float* trow = targets + ((size_t)b * O_ + tid) * 15;
    tx1[tid] = trow[0]; ty1[tid] = trow[1]; tx2[tid] = trow[2]; ty2[tid] = trow[3];
    #pragma unroll
    for (int k = 0; k < 10; ++k) tlm[tid][k] = trow[4 + k];
    tlbl[tid] = trow[14];
  }
  __syncthreads();

  float vx = 0.f, vy = 0.f, vz = 0.f, vw = 0.f;
  #pragma unroll
  for (int k = 0; k < KC_; ++k) {
    const unsigned p = (unsigned)((blockIdx.x * KC_ + k) * 256 + tid);
    const size_t bp = (size_t)b * P_ + p;
    const unsigned slot = ws->sortrank[p];
    const unsigned v = pb32[(size_t)b * P_ + slot];     // L2-resident slice
    const float ov = __uint_as_float(v & 0xFFFFFFC0u);
    const int idx = (int)(v & 0x3Fu);
    const bool pos = !(ov < THRESH_);
    const bool pos1 = pos && (tlbl[idx] > 0.f);

    float2 cf = reinterpret_cast<const float2*>(conf_data)[bp];
    vy += focal_term(cf, pos);
    if (pos) {
      float4 pr = reinterpret_cast<const float4*>(priors)[p];
      float4 loc = reinterpret_cast<const float4*>(loc_data)[bp];
      vx += giou_term(pr, loc, tx1[idx], ty1[idx], tx2[idx], ty2[idx]);
      if (pos1) {
        vw += 1.f;
        vz += landm_term(pr, landm_data + bp * 10, &tlm[idx][0]);
      }
    }
  }

  #pragma unroll
  for (int i = 32; i > 0; i >>= 1) {
    vx += __shfl_xor(vx, i);
    vy += __shfl_xor(vy, i);
    vz += __shfl_xor(vz, i);
    vw += __shfl_xor(vw, i);
  }
  const int wave = tid >> 6, lane = tid & 63;
  if (lane == 0) wsum[wave] = make_float4(vx, vy, vz, vw);
  __syncthreads();
  if (tid == 0) {
    float sx = 0.f, sy = 0.f, sz = 0.f, sw = 0.f;
    #pragma unroll
    for (int w = 0; w < 4; ++w) {
      sx += wsum[w].x; sy += wsum[w].y; sz += wsum[w].z; sw += wsum[w].w;
    }
    ws->part[(size_t)blockIdx.y * GX_ + blockIdx.x] = make_float4(sx, sy, sz, sw);
  }
}

// ------- forced-match correction (exact mirror of match semantics) ----------
__global__ __launch_bounds__(64) void k_fix(const float* __restrict__ loc_data,
                                            const float* __restrict__ conf_data,
                                            const float* __restrict__ landm_data,
                                            const float* __restrict__ priors,
                                            const float* __restrict__ targets,
                                            WSHdr* __restrict__ ws) {
  __shared__ float tsh[O_][5];
  __shared__ float tlbl[O_];
  __shared__ float tlm[O_][10];
  const int b = blockIdx.x;
  const int tid = threadIdx.x;
  if (tid < O_) {
    const float* trow = targets + ((size_t)b * O_ + tid) * 15;
    float x1 = trow[0], y1 = trow[1], x2 = trow[2], y2 = trow[3];
    tsh[tid][0] = x1; tsh[tid][1] = y1; tsh[tid][2] = x2; tsh[tid][3] = y2;
    tsh[tid][4] = (x2 - x1) * (y2 - y1);
    #pragma unroll
    for (int k = 0; k < 10; ++k) tlm[tid][k] = trow[4 + k];
    tlbl[tid] = trow[14];
  }
  __syncthreads();

  unsigned fp = 0xFFFFFFFFu;
  if (tid < O_)
    fp = 0xFFFFFFFFu - (unsigned)(ws->gkey[(size_t)b * O_ + tid] & 0xFFFFFFFFull);
  bool alive = tid < O_;
  for (int j2 = 0; j2 < O_; ++j2) {       // last-j-wins dedupe
    unsigned f2 = __shfl(fp, j2, 64);
    if (j2 > tid && f2 == fp) alive = false;
  }

  float dll = 0.f, dlc = 0.f, dllm = 0.f, dn1 = 0.f;
  if (alive) {
    const int p = (int)fp;
    const size_t bp = (size_t)b * P_ + p;
    float4 pr = reinterpret_cast<const float4*>(priors)[p];
    float px1 = pr.x - pr.z * 0.5f, py1 = pr.y - pr.w * 0.5f;
    float px2 = pr.x + pr.z * 0.5f, py2 = pr.y + pr.w * 0.5f;
    float pa = (px2 - px1) * (py2 - py1);
    float bov = 0.f;
    int bidx = 0;
    for (int o = 0; o < O_; ++o) {
      const float x1 = tsh[o][0], y1 = tsh[o][1], x2 = tsh[o][2], y2 = tsh[o][3];
      const float ta = tsh[o][4];
      float iw = fmaxf(fminf(x2, px2) - fmaxf(x1, px1), 0.f);
      float ih = fmaxf(fminf(y2, py2) - fmaxf(y1, py1), 0.f);
      float inter = iw * ih;
      float iou = inter * frcp(ta + pa - inter);
      if (iou > bov) { bov = iou; bidx = o; }
    }
    float2 cf = reinterpret_cast<const float2*>(conf_data)[bp];
    float4 loc = reinterpret_cast<const float4*>(loc_data)[bp];
    const float* lmrow = landm_data + bp * 10;
    // old (unforced) contribution — mirrors k_loss3 (incl. iou truncation)
    {
      const float ovt = __uint_as_float(__float_as_uint(bov) & 0xFFFFFFC0u);
      const bool pos = !(ovt < THRESH_);
      const bool pos1 = pos && (tlbl[bidx] > 0.f);
      dlc -= focal_term(cf, pos);
      if (pos) {
        dll -= giou_term(pr, loc, tsh[bidx][0], tsh[bidx][1], tsh[bidx][2], tsh[bidx][3]);
        if (pos1) {
          dn1 -= 1.f;
          dllm -= landm_term(pr, lmrow, &tlm[bidx][0]);
        }
      }
    }
    // new (forced) contribution: ov=2 -> pos, idx = tid
    {
      const int idx = tid;
      const bool pos1 = tlbl[idx] > 0.f;
      dlc += focal_term(cf, true);
      dll += giou_term(pr, loc, tsh[idx][0], tsh[idx][1], tsh[idx][2], tsh[idx][3]);
      if (pos1) {
        dn1 += 1.f;
        dllm += landm_term(pr, lmrow, &tlm[idx][0]);
      }
    }
  }
  #pragma unroll
  for (int i = 32; i > 0; i >>= 1) {
    dll += __shfl_xor(dll, i);
    dlc += __shfl_xor(dlc, i);
    dllm += __shfl_xor(dllm, i);
    dn1 += __shfl_xor(dn1, i);
  }
  if (tid == 0) {
    ws->corr[b][0] = (double)dll;
    ws->corr[b][1] = (double)dlc;
    ws->corr[b][2] = (double)dllm;
    ws->corr[b][3] = (double)dn1;
  }
}

// ------- final reduction ----------------------------------------------------
__global__ __launch_bounds__(256) void k_final(const WSHdr* __restrict__ ws,
                                               float* __restrict__ out) {
  __shared__ double sh[4][4];
  const int tid = threadIdx.x;
  double sx = 0.0, sy = 0.0, sz = 0.0, sw = 0.0;
  for (int i = tid; i < GX_ * B_; i += 256) {
    float4 v = ws->part[i];
    sx += v.x; sy += v.y; sz += v.z; sw += v.w;
  }
  if (tid < B_) {
    sx += ws->corr[tid][0];
    sy += ws->corr[tid][1];
    sz += ws->corr[tid][2];
    sw += ws->corr[tid][3];
  }
  #pragma unroll
  for (int i = 32; i > 0; i >>= 1) {
    sx += __shfl_xor(sx, i);
    sy += __shfl_xor(sy, i);
    sz += __shfl_xor(sz, i);
    sw += __shfl_xor(sw, i);
  }
  const int wave = tid >> 6, lane = tid & 63;
  if (lane == 0) { sh[wave][0] = sx; sh[wave][1] = sy; sh[wave][2] = sz; sh[wave][3] = sw; }
  __syncthreads();
  if (tid == 0) {
    double ax = 0, ay = 0, az = 0, aw = 0;
    #pragma unroll
    for (int w = 0; w < 4; ++w) { ax += sh[w][0]; ay += sh[w][1]; az += sh[w][2]; aw += sh[w][3]; }
    double n1 = aw < 1.0 ? 1.0 : aw;
    out[0] = (float)(2.0 * ax / n1);
    out[1] = (float)(ay / n1);
    out[2] = (float)(az / n1);
  }
}

extern "C" void kernel_launch(void* const* d_in, const int* in_sizes, int n_in,
                              void* d_out, int out_size, void* d_ws, size_t ws_size,
                              hipStream_t stream) {
  (void)in_sizes; (void)n_in; (void)out_size; (void)ws_size;
  const float* loc     = (const float*)d_in[0];
  const float* conf    = (const float*)d_in[1];
  const float* landm   = (const float*)d_in[2];
  const float* priors  = (const float*)d_in[3];
  const float* targets = (const float*)d_in[4];
  WSHdr* ws = (WSHdr*)d_ws;
  unsigned* aux = (unsigned*)((char*)d_ws + sizeof(WSHdr));  // pb32; head = cellid
  float* out = (float*)d_out;

  hipLaunchKernelGGL(k_hist, dim3(HB_), dim3(256), 0, stream, priors, ws, aux);
  hipLaunchKernelGGL(k_scan2, dim3(1), dim3(256), 0, stream, ws);
  hipLaunchKernelGGL(k_scatter2, dim3(HB_), dim3(256), 0, stream, priors, ws, aux);
  hipLaunchKernelGGL(k_match2, dim3(GX_, B_), dim3(256), 0, stream,
                     targets, ws, aux);
  hipLaunchKernelGGL(k_loss3, dim3(GX_, B_), dim3(256), 0, stream,
                     loc, conf, landm, priors, targets, ws, aux);
  hipLaunchKernelGGL(k_fix, dim3(B_), dim3(64), 0, stream,
                     loc, conf, landm, priors, targets, ws);
  hipLaunchKernelGGL(k_final, dim3(1), dim3(256), 0, stream, ws, out);
}

// Round 13
// 71.568 us; speedup vs baseline: 1.4695x; 1.4695x over previous
//
#include <hip/hip_runtime.h>
#include <cstdint>

#define B_ 32
#define P_ 65536
#define O_ 32
#define GX_ 64            // 64 chunk-blocks per batch; 1024 sorted priors each
#define KC_ 4             // consecutive sorted priors per thread
#define NXCD_ 8
#define NCELL_ 16
#define NC_ (NCELL_ * NCELL_)
#define HB_ 32            // histogram/scatter blocks
#define PPH_ (P_ / (HB_ * 256))   // 8 priors per thread in hist/scatter
#define MARGIN_ 0.1501f   // max prior half-extent (wh<=0.3) + slack
#define THRESH_ 0.35f
#define VAR0 0.1f
#define VAR1 0.2f
#define EPS_ 1e-7f
#define ALPHA_ 0.25f

struct WSHdr {
  unsigned long long gkey[B_ * O_];  // per (b,o): (iou_bits<<32)|(~p)
  float4 part[GX_ * B_];             // per-block partials (ll, lc, llm, n1)
  double corr[B_][4];                // per-batch forced-match corrections
  unsigned blkcnt[HB_ * NC_];
  unsigned blkbase[HB_ * NC_];
  unsigned cellid[P_];
  unsigned idx_sorted[P_];
  float4 priors_sorted[P_];
};

__device__ __forceinline__ float frcp(float x) { return __builtin_amdgcn_rcpf(x); }

template <int CTRL>
__device__ __forceinline__ float dpp_fmax(float v) {
  int s = __builtin_amdgcn_update_dpp(0, __float_as_int(v), CTRL, 0xF, 0xF, true);
  return fmaxf(v, __int_as_float(s));
}
template <int CTRL>
__device__ __forceinline__ unsigned dpp_umax(unsigned v) {
  unsigned u = (unsigned)__builtin_amdgcn_update_dpp(0, (int)v, CTRL, 0xF, 0xF, true);
  return u > v ? u : v;
}

// ---- shared loss math (identical expressions everywhere) --------------------
__device__ __forceinline__ float focal_term(float2 cf, bool pos) {
  float mx = fmaxf(cf.x, cf.y);
  float lse = mx + __logf(1.f + __expf(-fabsf(cf.x - cf.y)));
  float logpt = (pos ? cf.y : cf.x) - lse;
  float pt = __expf(logpt);
  float om = 1.f - pt;
  return -ALPHA_ * om * sqrtf(om) * logpt;
}

__device__ __forceinline__ float giou_term(float4 pr, float4 loc,
                                           float b2x1, float b2y1,
                                           float b2x2, float b2y2) {
  float dx = pr.x + loc.x * VAR0 * pr.z;
  float dy = pr.y + loc.y * VAR0 * pr.w;
  float dw = pr.z * __expf(loc.z * VAR1);
  float dh = pr.w * __expf(loc.w * VAR1);
  float b1x1 = dx - dw * 0.5f, b1y1 = dy - dh * 0.5f;
  float b1x2 = dx + dw * 0.5f, b1y2 = dy + dh * 0.5f;
  float a1 = (b1x2 - b1x1) * (b1y2 - b1y1);
  float a2 = (b2x2 - b2x1) * (b2y2 - b2y1);
  float iw = fmaxf(fminf(b1x2, b2x2) - fmaxf(b1x1, b2x1), 0.f);
  float ih = fmaxf(fminf(b1y2, b2y2) - fmaxf(b1y1, b2y1), 0.f);
  float inter = iw * ih;
  float uni = a1 + a2 - inter;
  float iou = inter * frcp(uni + EPS_);
  float ew = fmaxf(b1x2, b2x2) - fminf(b1x1, b2x1);
  float eh = fmaxf(b1y2, b2y2) - fminf(b1y1, b2y1);
  float enc = ew * eh;
  float g = iou - (enc - uni) * frcp(enc + EPS_);
  return 1.f - g;
}

__device__ __forceinline__ float landm_term(float4 pr,
                                            const float* __restrict__ lmrow,
                                            const float* __restrict__ tlm_row) {
  float rw = frcp(VAR0 * pr.z);
  float rh = frcp(VAR0 * pr.w);
  float llm = 0.f;
  #pragma unroll
  for (int q = 0; q < 5; ++q) {
    float2 d = *reinterpret_cast<const float2*>(lmrow + q * 2);
    float ex = d.x - (tlm_row[2 * q] - pr.x) * rw;
    float ey = d.y - (tlm_row[2 * q + 1] - pr.y) * rh;
    float ax = fabsf(ex), ay = fabsf(ey);
    llm += (ax < 1.f) ? 0.5f * ex * ex : ax - 0.5f;
    llm += (ay < 1.f) ? 0.5f * ey * ey : ay - 0.5f;
  }
  return llm;
}

// ===================== sort prep (batch-independent) ========================

__global__ __launch_bounds__(256) void k_init2(WSHdr* ws) {
  const int t = blockIdx.x * 256 + threadIdx.x;     // grid 4
  if (t < B_ * O_) ws->gkey[t] = 0xFFFFFFFFull;     // seed: (iou=0, p=0)
}

__global__ __launch_bounds__(256) void k_hist(const float* __restrict__ priors,
                                              WSHdr* __restrict__ ws) {
  __shared__ unsigned lh[NC_];
  const int tid = threadIdx.x;
  lh[tid] = 0u;
  __syncthreads();
  const int pb0 = blockIdx.x * (256 * PPH_);
  #pragma unroll
  for (int i = 0; i < PPH_; ++i) {
    const int p = pb0 + i * 256 + tid;
    float4 pr = reinterpret_cast<const float4*>(priors)[p];
    int cx = min(NCELL_ - 1, max(0, (int)(pr.x * (float)NCELL_)));
    int cy = min(NCELL_ - 1, max(0, (int)(pr.y * (float)NCELL_)));
    unsigned c = (unsigned)(cy * NCELL_ + cx);
    ws->cellid[p] = c;
    atomicAdd(&lh[c], 1u);
  }
  __syncthreads();
  ws->blkcnt[blockIdx.x * NC_ + tid] = lh[tid];
}

__global__ __launch_bounds__(256) void k_scan2(WSHdr* ws) {
  __shared__ unsigned s[NC_];
  const int c = threadIdx.x;
  unsigned tot = 0;
  for (int blk = 0; blk < HB_; ++blk) tot += ws->blkcnt[blk * NC_ + c];
  s[c] = tot;
  __syncthreads();
  for (int off = 1; off < NC_; off <<= 1) {
    unsigned t = (c >= off) ? s[c - off] : 0u;
    __syncthreads();
    s[c] += t;
    __syncthreads();
  }
  unsigned run = s[c] - tot;   // exclusive cell base
  for (int blk = 0; blk < HB_; ++blk) {
    ws->blkbase[blk * NC_ + c] = run;
    run += ws->blkcnt[blk * NC_ + c];
  }
}

__global__ __launch_bounds__(256) void k_scatter2(const float* __restrict__ priors,
                                                  WSHdr* __restrict__ ws) {
  __shared__ unsigned lcur[NC_];
  const int tid = threadIdx.x;
  lcur[tid] = ws->blkbase[blockIdx.x * NC_ + tid];
  __syncthreads();
  const int pb0 = blockIdx.x * (256 * PPH_);
  #pragma unroll
  for (int i = 0; i < PPH_; ++i) {
    const int p = pb0 + i * 256 + tid;
    unsigned c = ws->cellid[p];
    unsigned slot = atomicAdd(&lcur[c], 1u);
    ws->idx_sorted[slot] = (unsigned)p;
    ws->priors_sorted[slot] = reinterpret_cast<const float4*>(priors)[p];
  }
}

// ===================== fused match + unforced losses ========================
// 1D grid, XCD-aware mapping: all 64 blocks of a batch land on ONE XCD so its
// conf/loc/landm slices are fetched into exactly one L2 (no 8x replication).
__global__ __launch_bounds__(256) void k_fused2(const float* __restrict__ loc_data,
                                                const float* __restrict__ conf_data,
                                                const float* __restrict__ landm_data,
                                                const float* __restrict__ targets,
                                                WSHdr* __restrict__ ws) {
  __shared__ float tsh[O_][4];
  __shared__ float tlbl[O_];
  __shared__ float tlm[O_][10];
  __shared__ unsigned long long kq[O_][17];
  __shared__ float4 wsum[4];
  const int bid = blockIdx.x;
  const int xcd = bid & (NXCD_ - 1);
  const int j = bid >> 3;
  const int b = xcd * (B_ / NXCD_) + (j & (B_ / NXCD_ - 1));  // 4 b's per XCD
  const int bx = j >> 2;                                       // 0..63
  const int tid = threadIdx.x;
  const int lane = tid & 63, wid = tid >> 6;
  if (tid < O_) {
    const float* trow = targets + ((size_t)b * O_ + tid) * 15;
    tsh[tid][0] = trow[0]; tsh[tid][1] = trow[1];
    tsh[tid][2] = trow[2]; tsh[tid][3] = trow[3];
    #pragma unroll
    for (int k = 0; k < 10; ++k) tlm[tid][k] = trow[4 + k];
    tlbl[tid] = trow[14];
  }
  for (int i = tid; i < O_ * 17; i += 256) ((unsigned long long*)kq)[i] = 0ull;
  __syncthreads();

  // 4 consecutive sorted priors per thread
  const int slot0 = bx * 1024 + tid * KC_;
  float4 pr[KC_];
  float px1[KC_], py1[KC_], px2[KC_], py2[KC_], pa[KC_], bov[KC_];
  int bidx[KC_];
  unsigned pinv[KC_];
  uint4 opv = *reinterpret_cast<const uint4*>(&ws->idx_sorted[slot0]);
  pinv[0] = 0xFFFFFFFFu - opv.x; pinv[1] = 0xFFFFFFFFu - opv.y;
  pinv[2] = 0xFFFFFFFFu - opv.z; pinv[3] = 0xFFFFFFFFu - opv.w;
  float mnx = 1e9f, mxx = -1e9f, mny = 1e9f, mxy = -1e9f;
  #pragma unroll
  for (int k = 0; k < KC_; ++k) {
    pr[k] = ws->priors_sorted[slot0 + k];
    px1[k] = pr[k].x - pr[k].z * 0.5f; py1[k] = pr[k].y - pr[k].w * 0.5f;
    px2[k] = pr[k].x + pr[k].z * 0.5f; py2[k] = pr[k].y + pr[k].w * 0.5f;
    pa[k] = (px2[k] - px1[k]) * (py2[k] - py1[k]);
    bov[k] = 0.f; bidx[k] = 0;
    mnx = fminf(mnx, pr[k].x); mxx = fmaxf(mxx, pr[k].x);
    mny = fminf(mny, pr[k].y); mxy = fmaxf(mxy, pr[k].y);
  }
  // wave bbox of prior centers (64-lane butterfly)
  #pragma unroll
  for (int i = 1; i < 64; i <<= 1) {
    mnx = fminf(mnx, __shfl_xor(mnx, i));
    mxx = fmaxf(mxx, __shfl_xor(mxx, i));
    mny = fminf(mny, __shfl_xor(mny, i));
    mxy = fmaxf(mxy, __shfl_xor(mxy, i));
  }

  const float* __restrict__ tb = targets + (size_t)b * O_ * 15;
  for (int o = 0; o < O_; ++o) {
    const float x1 = tb[o * 15 + 0], y1 = tb[o * 15 + 1];
    const float x2 = tb[o * 15 + 2], y2 = tb[o * 15 + 3];
    // wave-uniform conservative cull: expanded truth vs wave center-bbox
    bool hit = (x1 - MARGIN_ <= mxx) && (x2 + MARGIN_ >= mnx) &&
               (y1 - MARGIN_ <= mxy) && (y2 + MARGIN_ >= mny);
    if (hit) {
      const float ta = (x2 - x1) * (y2 - y1);
      float tiou = 0.f;
      unsigned tinv = 0u;
      #pragma unroll
      for (int k = 0; k < KC_; ++k) {
        float iw = fmaxf(fminf(x2, px2[k]) - fmaxf(x1, px1[k]), 0.f);
        float ih = fmaxf(fminf(y2, py2[k]) - fmaxf(y1, py1[k]), 0.f);
        float inter = iw * ih;
        float iou = inter * frcp(ta + pa[k] - inter);
        if (iou > bov[k]) { bov[k] = iou; bidx[k] = o; }      // o ascending
        if (iou > tiou || (iou == tiou && pinv[k] > tinv)) {  // min-p tie
          tiou = iou; tinv = pinv[k];
        }
      }
      // two-phase exact row reduce: max iou, then min p among max lanes
      float m = tiou;
      m = dpp_fmax<0x128>(m);
      m = dpp_fmax<0x124>(m);
      m = dpp_fmax<0x122>(m);
      m = dpp_fmax<0x121>(m);
      unsigned cand = (tiou == m) ? tinv : 0u;
      cand = dpp_umax<0x128>(cand);
      cand = dpp_umax<0x124>(cand);
      cand = dpp_umax<0x122>(cand);
      cand = dpp_umax<0x121>(cand);
      if ((lane & 15) == 0)
        kq[o][wid * 4 + (lane >> 4)] =
            ((unsigned long long)__float_as_uint(m) << 32) |
            (unsigned long long)cand;
    }
  }

  // ---- losses with UNFORCED (bov,bidx); k_fix corrects forced priors ----
  float vx = 0.f, vy = 0.f, vz = 0.f, vw = 0.f;
  #pragma unroll
  for (int k = 0; k < KC_; ++k) {
    const unsigned p = 0xFFFFFFFFu - pinv[k];
    const size_t bp = (size_t)b * P_ + p;
    const float ov = bov[k];
    const int idx = bidx[k];
    const bool pos = !(ov < THRESH_);
    const bool pos1 = pos && (tlbl[idx] > 0.f);
    float2 cf = reinterpret_cast<const float2*>(conf_data)[bp];
    vy += focal_term(cf, pos);
    if (pos) {
      float4 loc = reinterpret_cast<const float4*>(loc_data)[bp];
      vx += giou_term(pr[k], loc, tsh[idx][0], tsh[idx][1], tsh[idx][2], tsh[idx][3]);
      if (pos1) {
        vw += 1.f;
        vz += landm_term(pr[k], landm_data + bp * 10, &tlm[idx][0]);
      }
    }
  }

  __syncthreads();
  if (tid < O_) {
    unsigned long long best = kq[tid][0];
    #pragma unroll
    for (int s = 1; s < 16; ++s) {
      unsigned long long v = kq[tid][s];
      if (v > best) best = v;
    }
    atomicMax(&ws->gkey[(size_t)b * O_ + tid], best);
  }

  #pragma unroll
  for (int i = 32; i > 0; i >>= 1) {
    vx += __shfl_xor(vx, i);
    vy += __shfl_xor(vy, i);
    vz += __shfl_xor(vz, i);
    vw += __shfl_xor(vw, i);
  }
  if (lane == 0) wsum[wid] = make_float4(vx, vy, vz, vw);
  __syncthreads();
  if (tid == 0) {
    float sx = 0.f, sy = 0.f, sz = 0.f, sw = 0.f;
    #pragma unroll
    for (int w = 0; w < 4; ++w) {
      sx += wsum[w].x; sy += wsum[w].y; sz += wsum[w].z; sw += wsum[w].w;
    }
    ws->part[(size_t)b * GX_ + bx] = make_float4(sx, sy, sz, sw);
  }
}

// ------- forced-match correction (exact mirror of fused semantics) ----------
__global__ __launch_bounds__(64) void k_fix(const float* __restrict__ loc_data,
                                            const float* __restrict__ conf_data,
                                            const float* __restrict__ landm_data,
                                            const float* __restrict__ priors,
                                            const float* __restrict__ targets,
                                            WSHdr* __restrict__ ws) {
  __shared__ float tsh[O_][5];
  __shared__ float tlbl[O_];
  __shared__ float tlm[O_][10];
  const int b = blockIdx.x;
  const int tid = threadIdx.x;
  if (tid < O_) {
    const float* trow = targets + ((size_t)b * O_ + tid) * 15;
    float x1 = trow[0], y1 = trow[1], x2 = trow[2], y2 = trow[3];
    tsh[tid][0] = x1; tsh[tid][1] = y1; tsh[tid][2] = x2; tsh[tid][3] = y2;
    tsh[tid][4] = (x2 - x1) * (y2 - y1);
    #pragma unroll
    for (int k = 0; k < 10; ++k) tlm[tid][k] = trow[4 + k];
    tlbl[tid] = trow[14];
  }
  __syncthreads();

  unsigned fp = 0xFFFFFFFFu;
  if (tid < O_)
    fp = 0xFFFFFFFFu - (unsigned)(ws->gkey[(size_t)b * O_ + tid] & 0xFFFFFFFFull);
  bool alive = tid < O_;
  for (int j2 = 0; j2 < O_; ++j2) {       // last-j-wins dedupe
    unsigned f2 = __shfl(fp, j2, 64);
    if (j2 > tid && f2 == fp) alive = false;
  }

  float dll = 0.f, dlc = 0.f, dllm = 0.f, dn1 = 0.f;
  if (alive) {
    const int p = (int)fp;
    const size_t bp = (size_t)b * P_ + p;
    float4 pr = reinterpret_cast<const float4*>(priors)[p];
    float px1 = pr.x - pr.z * 0.5f, py1 = pr.y - pr.w * 0.5f;
    float px2 = pr.x + pr.z * 0.5f, py2 = pr.y + pr.w * 0.5f;
    float pa = (px2 - px1) * (py2 - py1);
    float bov = 0.f;
    int bidx = 0;
    for (int o = 0; o < O_; ++o) {
      const float x1 = tsh[o][0], y1 = tsh[o][1], x2 = tsh[o][2], y2 = tsh[o][3];
      const float ta = tsh[o][4];
      float iw = fmaxf(fminf(x2, px2) - fmaxf(x1, px1), 0.f);
      float ih = fmaxf(fminf(y2, py2) - fmaxf(y1, py1), 0.f);
      float inter = iw * ih;
      float iou = inter * frcp(ta + pa - inter);
      if (iou > bov) { bov = iou; bidx = o; }
    }
    float2 cf = reinterpret_cast<const float2*>(conf_data)[bp];
    float4 loc = reinterpret_cast<const float4*>(loc_data)[bp];
    const float* lmrow = landm_data + bp * 10;
    {
      const bool pos = !(bov < THRESH_);
      const bool pos1 = pos && (tlbl[bidx] > 0.f);
      dlc -= focal_term(cf, pos);
      if (pos) {
        dll -= giou_term(pr, loc, tsh[bidx][0], tsh[bidx][1], tsh[bidx][2], tsh[bidx][3]);
        if (pos1) {
          dn1 -= 1.f;
          dllm -= landm_term(pr, lmrow, &tlm[bidx][0]);
        }
      }
    }
    {
      const int idx = tid;
      const bool pos1 = tlbl[idx] > 0.f;
      dlc += focal_term(cf, true);
      dll += giou_term(pr, loc, tsh[idx][0], tsh[idx][1], tsh[idx][2], tsh[idx][3]);
      if (pos1) {
        dn1 += 1.f;
        dllm += landm_term(pr, lmrow, &tlm[idx][0]);
      }
    }
  }
  #pragma unroll
  for (int i = 32; i > 0; i >>= 1) {
    dll += __shfl_xor(dll, i);
    dlc += __shfl_xor(dlc, i);
    dllm += __shfl_xor(dllm, i);
    dn1 += __shfl_xor(dn1, i);
  }
  if (tid == 0) {
    ws->corr[b][0] = (double)dll;
    ws->corr[b][1] = (double)dlc;
    ws->corr[b][2] = (double)dllm;
    ws->corr[b][3] = (double)dn1;
  }
}

// ------- final reduction ----------------------------------------------------
__global__ __launch_bounds__(256) void k_final(const WSHdr* __restrict__ ws,
                                               float* __restrict__ out) {
  __shared__ double sh[4][4];
  const int tid = threadIdx.x;
  double sx = 0.0, sy = 0.0, sz = 0.0, sw = 0.0;
  for (int i = tid; i < GX_ * B_; i += 256) {
    float4 v = ws->part[i];
    sx += v.x; sy += v.y; sz += v.z; sw += v.w;
  }
  if (tid < B_) {
    sx += ws->corr[tid][0];
    sy += ws->corr[tid][1];
    sz += ws->corr[tid][2];
    sw += ws->corr[tid][3];
  }
  #pragma unroll
  for (int i = 32; i > 0; i >>= 1) {
    sx += __shfl_xor(sx, i);
    sy += __shfl_xor(sy, i);
    sz += __shfl_xor(sz, i);
    sw += __shfl_xor(sw, i);
  }
  const int wave = tid >> 6, lane = tid & 63;
  if (lane == 0) { sh[wave][0] = sx; sh[wave][1] = sy; sh[wave][2] = sz; sh[wave][3] = sw; }
  __syncthreads();
  if (tid == 0) {
    double ax = 0, ay = 0, az = 0, aw = 0;
    #pragma unroll
    for (int w = 0; w < 4; ++w) { ax += sh[w][0]; ay += sh[w][1]; az += sh[w][2]; aw += sh[w][3]; }
    double n1 = aw < 1.0 ? 1.0 : aw;
    out[0] = (float)(2.0 * ax / n1);
    out[1] = (float)(ay / n1);
    out[2] = (float)(az / n1);
  }
}

extern "C" void kernel_launch(void* const* d_in, const int* in_sizes, int n_in,
                              void* d_out, int out_size, void* d_ws, size_t ws_size,
                              hipStream_t stream) {
  (void)in_sizes; (void)n_in; (void)out_size; (void)ws_size;
  const float* loc     = (const float*)d_in[0];
  const float* conf    = (const float*)d_in[1];
  const float* landm   = (const float*)d_in[2];
  const float* priors  = (const float*)d_in[3];
  const float* targets = (const float*)d_in[4];
  WSHdr* ws = (WSHdr*)d_ws;
  float* out = (float*)d_out;

  hipLaunchKernelGGL(k_init2, dim3(4), dim3(256), 0, stream, ws);
  hipLaunchKernelGGL(k_hist, dim3(HB_), dim3(256), 0, stream, priors, ws);
  hipLaunchKernelGGL(k_scan2, dim3(1), dim3(256), 0, stream, ws);
  hipLaunchKernelGGL(k_scatter2, dim3(HB_), dim3(256), 0, stream, priors, ws);
  hipLaunchKernelGGL(k_fused2, dim3(GX_ * B_), dim3(256), 0, stream,
                     loc, conf, landm, targets, ws);
  hipLaunchKernelGGL(k_fix, dim3(B_), dim3(64), 0, stream,
                     loc, conf, landm, priors, targets, ws);
  hipLaunchKernelGGL(k_final, dim3(1), dim3(256), 0, stream, ws, out);
}

// Round 14
// 71.555 us; speedup vs baseline: 1.4698x; 1.0002x over previous
//
#include <hip/hip_runtime.h>
#include <cstdint>

#define B_ 32
#define P_ 65536
#define O_ 32
#define GX_ 64            // 64 chunk-blocks per batch; 1024 sorted priors each
#define KC_ 4             // consecutive sorted priors per thread
#define NXCD_ 8
#define NCELL_ 16
#define NC_ (NCELL_ * NCELL_)
#define HB_ 32            // histogram/scatter blocks
#define PPH_ (P_ / (HB_ * 256))   // 8 priors per thread in hist/scatter
#define MARGIN_ 0.1501f   // max prior half-extent (wh<=0.3) + slack
#define THRESH_ 0.35f
#define VAR0 0.1f
#define VAR1 0.2f
#define EPS_ 1e-7f
#define ALPHA_ 0.25f

struct WSHdr {
  unsigned long long gkey[B_ * O_];  // per (b,o): (iou_bits<<32)|(~p)
  float4 part[GX_ * B_];             // per-block partials (ll, lc, llm, n1)
  double corr[B_][4];                // per-batch forced-match corrections
  unsigned blkcnt[HB_ * NC_];
  unsigned blkbase[HB_ * NC_];       // (unused now; kept for layout stability)
  unsigned cellid[P_];
  unsigned idx_sorted[P_];
  float4 priors_sorted[P_];
};

__device__ __forceinline__ float frcp(float x) { return __builtin_amdgcn_rcpf(x); }

template <int CTRL>
__device__ __forceinline__ float dpp_fmax(float v) {
  int s = __builtin_amdgcn_update_dpp(0, __float_as_int(v), CTRL, 0xF, 0xF, true);
  return fmaxf(v, __int_as_float(s));
}
template <int CTRL>
__device__ __forceinline__ unsigned dpp_umax(unsigned v) {
  unsigned u = (unsigned)__builtin_amdgcn_update_dpp(0, (int)v, CTRL, 0xF, 0xF, true);
  return u > v ? u : v;
}

// ---- shared loss math (identical expressions everywhere) --------------------
__device__ __forceinline__ float focal_term(float2 cf, bool pos) {
  float mx = fmaxf(cf.x, cf.y);
  float lse = mx + __logf(1.f + __expf(-fabsf(cf.x - cf.y)));
  float logpt = (pos ? cf.y : cf.x) - lse;
  float pt = __expf(logpt);
  float om = 1.f - pt;
  return -ALPHA_ * om * sqrtf(om) * logpt;
}

__device__ __forceinline__ float giou_term(float4 pr, float4 loc,
                                           float b2x1, float b2y1,
                                           float b2x2, float b2y2) {
  float dx = pr.x + loc.x * VAR0 * pr.z;
  float dy = pr.y + loc.y * VAR0 * pr.w;
  float dw = pr.z * __expf(loc.z * VAR1);
  float dh = pr.w * __expf(loc.w * VAR1);
  float b1x1 = dx - dw * 0.5f, b1y1 = dy - dh * 0.5f;
  float b1x2 = dx + dw * 0.5f, b1y2 = dy + dh * 0.5f;
  float a1 = (b1x2 - b1x1) * (b1y2 - b1y1);
  float a2 = (b2x2 - b2x1) * (b2y2 - b2y1);
  float iw = fmaxf(fminf(b1x2, b2x2) - fmaxf(b1x1, b2x1), 0.f);
  float ih = fmaxf(fminf(b1y2, b2y2) - fmaxf(b1y1, b2y1), 0.f);
  float inter = iw * ih;
  float uni = a1 + a2 - inter;
  float iou = inter * frcp(uni + EPS_);
  float ew = fmaxf(b1x2, b2x2) - fminf(b1x1, b2x1);
  float eh = fmaxf(b1y2, b2y2) - fminf(b1y1, b2y1);
  float enc = ew * eh;
  float g = iou - (enc - uni) * frcp(enc + EPS_);
  return 1.f - g;
}

__device__ __forceinline__ float landm_term(float4 pr,
                                            const float* __restrict__ lmrow,
                                            const float* __restrict__ tlm_row) {
  float rw = frcp(VAR0 * pr.z);
  float rh = frcp(VAR0 * pr.w);
  float llm = 0.f;
  #pragma unroll
  for (int q = 0; q < 5; ++q) {
    float2 d = *reinterpret_cast<const float2*>(lmrow + q * 2);
    float ex = d.x - (tlm_row[2 * q] - pr.x) * rw;
    float ey = d.y - (tlm_row[2 * q + 1] - pr.y) * rh;
    float ax = fabsf(ex), ay = fabsf(ey);
    llm += (ax < 1.f) ? 0.5f * ex * ex : ax - 0.5f;
    llm += (ay < 1.f) ? 0.5f * ey * ey : ay - 0.5f;
  }
  return llm;
}

// ===================== sort prep (batch-independent) ========================

__global__ __launch_bounds__(256) void k_hist(const float* __restrict__ priors,
                                              WSHdr* __restrict__ ws) {
  __shared__ unsigned lh[NC_];
  const int tid = threadIdx.x;
  lh[tid] = 0u;
  if (blockIdx.x == 0) {          // fold gkey seed into first hist block
    for (int i = tid; i < B_ * O_; i += 256) ws->gkey[i] = 0xFFFFFFFFull;
  }
  __syncthreads();
  const int pb0 = blockIdx.x * (256 * PPH_);
  #pragma unroll
  for (int i = 0; i < PPH_; ++i) {
    const int p = pb0 + i * 256 + tid;
    float4 pr = reinterpret_cast<const float4*>(priors)[p];
    int cx = min(NCELL_ - 1, max(0, (int)(pr.x * (float)NCELL_)));
    int cy = min(NCELL_ - 1, max(0, (int)(pr.y * (float)NCELL_)));
    unsigned c = (unsigned)(cy * NCELL_ + cx);
    ws->cellid[p] = c;
    atomicAdd(&lh[c], 1u);
  }
  __syncthreads();
  ws->blkcnt[blockIdx.x * NC_ + tid] = lh[tid];
}

// scatter with local scan fold: each block recomputes the cell bases from
// blkcnt (kernel boundary guarantees k_hist completion). Deterministic.
__global__ __launch_bounds__(256) void k_scatter2(const float* __restrict__ priors,
                                                  WSHdr* __restrict__ ws) {
  __shared__ unsigned lcur[NC_];
  __shared__ unsigned s[NC_];
  const int tid = threadIdx.x;       // == cell id (NC_ == 256)
  unsigned totc = 0u, pre = 0u;
  for (int blk = 0; blk < HB_; ++blk) {
    unsigned v = ws->blkcnt[blk * NC_ + tid];
    if (blk < (int)blockIdx.x) pre += v;
    totc += v;
  }
  s[tid] = totc;
  __syncthreads();
  for (int off = 1; off < NC_; off <<= 1) {
    unsigned t = (tid >= off) ? s[tid - off] : 0u;
    __syncthreads();
    s[tid] += t;
    __syncthreads();
  }
  lcur[tid] = (s[tid] - totc) + pre;   // global cell base + this block's offset
  __syncthreads();
  const int pb0 = blockIdx.x * (256 * PPH_);
  #pragma unroll
  for (int i = 0; i < PPH_; ++i) {
    const int p = pb0 + i * 256 + tid;
    unsigned c = ws->cellid[p];
    unsigned slot = atomicAdd(&lcur[c], 1u);
    ws->idx_sorted[slot] = (unsigned)p;
    ws->priors_sorted[slot] = reinterpret_cast<const float4*>(priors)[p];
  }
}

// ===================== fused match + unforced losses ========================
// 1D grid, XCD-aware B-MAJOR mapping: all 64 blocks of a batch dispatch
// consecutively on ONE XCD -> at most ~2 conf slices live per L2 at a time.
__global__ __launch_bounds__(256) void k_fused2(const float* __restrict__ loc_data,
                                                const float* __restrict__ conf_data,
                                                const float* __restrict__ landm_data,
                                                const float* __restrict__ targets,
                                                WSHdr* __restrict__ ws) {
  __shared__ float tsh[O_][4];
  __shared__ float tlbl[O_];
  __shared__ float tlm[O_][10];
  __shared__ unsigned long long kq[O_][17];
  __shared__ float4 wsum[4];
  const int bid = blockIdx.x;
  const int xcd = bid & (NXCD_ - 1);
  const int j = bid >> 3;                         // 0..255
  const int b = xcd * (B_ / NXCD_) + (j >> 6);    // b-major: slow b
  const int bx = j & 63;                          // 0..63 chunk within batch
  const int tid = threadIdx.x;
  const int lane = tid & 63, wid = tid >> 6;
  if (tid < O_) {
    const float* trow = targets + ((size_t)b * O_ + tid) * 15;
    tsh[tid][0] = trow[0]; tsh[tid][1] = trow[1];
    tsh[tid][2] = trow[2]; tsh[tid][3] = trow[3];
    #pragma unroll
    for (int k = 0; k < 10; ++k) tlm[tid][k] = trow[4 + k];
    tlbl[tid] = trow[14];
  }
  for (int i = tid; i < O_ * 17; i += 256) ((unsigned long long*)kq)[i] = 0ull;
  __syncthreads();

  // 4 consecutive sorted priors per thread
  const int slot0 = bx * 1024 + tid * KC_;
  float4 pr[KC_];
  float px1[KC_], py1[KC_], px2[KC_], py2[KC_], pa[KC_], bov[KC_];
  int bidx[KC_];
  unsigned pinv[KC_];
  uint4 opv = *reinterpret_cast<const uint4*>(&ws->idx_sorted[slot0]);
  pinv[0] = 0xFFFFFFFFu - opv.x; pinv[1] = 0xFFFFFFFFu - opv.y;
  pinv[2] = 0xFFFFFFFFu - opv.z; pinv[3] = 0xFFFFFFFFu - opv.w;
  float mnx = 1e9f, mxx = -1e9f, mny = 1e9f, mxy = -1e9f;
  #pragma unroll
  for (int k = 0; k < KC_; ++k) {
    pr[k] = ws->priors_sorted[slot0 + k];
    px1[k] = pr[k].x - pr[k].z * 0.5f; py1[k] = pr[k].y - pr[k].w * 0.5f;
    px2[k] = pr[k].x + pr[k].z * 0.5f; py2[k] = pr[k].y + pr[k].w * 0.5f;
    pa[k] = (px2[k] - px1[k]) * (py2[k] - py1[k]);
    bov[k] = 0.f; bidx[k] = 0;
    mnx = fminf(mnx, pr[k].x); mxx = fmaxf(mxx, pr[k].x);
    mny = fminf(mny, pr[k].y); mxy = fmaxf(mxy, pr[k].y);
  }
  // wave bbox of prior centers (64-lane butterfly)
  #pragma unroll
  for (int i = 1; i < 64; i <<= 1) {
    mnx = fminf(mnx, __shfl_xor(mnx, i));
    mxx = fmaxf(mxx, __shfl_xor(mxx, i));
    mny = fminf(mny, __shfl_xor(mny, i));
    mxy = fmaxf(mxy, __shfl_xor(mxy, i));
  }

  const float* __restrict__ tb = targets + (size_t)b * O_ * 15;
  for (int o = 0; o < O_; ++o) {
    const float x1 = tb[o * 15 + 0], y1 = tb[o * 15 + 1];
    const float x2 = tb[o * 15 + 2], y2 = tb[o * 15 + 3];
    // wave-uniform conservative cull: expanded truth vs wave center-bbox
    bool hit = (x1 - MARGIN_ <= mxx) && (x2 + MARGIN_ >= mnx) &&
               (y1 - MARGIN_ <= mxy) && (y2 + MARGIN_ >= mny);
    if (hit) {
      const float ta = (x2 - x1) * (y2 - y1);
      float tiou = 0.f;
      unsigned tinv = 0u;
      #pragma unroll
      for (int k = 0; k < KC_; ++k) {
        float iw = fmaxf(fminf(x2, px2[k]) - fmaxf(x1, px1[k]), 0.f);
        float ih = fmaxf(fminf(y2, py2[k]) - fmaxf(y1, py1[k]), 0.f);
        float inter = iw * ih;
        float iou = inter * frcp(ta + pa[k] - inter);
        if (iou > bov[k]) { bov[k] = iou; bidx[k] = o; }      // o ascending
        if (iou > tiou || (iou == tiou && pinv[k] > tinv)) {  // min-p tie
          tiou = iou; tinv = pinv[k];
        }
      }
      // two-phase exact row reduce: max iou, then min p among max lanes
      float m = tiou;
      m = dpp_fmax<0x128>(m);
      m = dpp_fmax<0x124>(m);
      m = dpp_fmax<0x122>(m);
      m = dpp_fmax<0x121>(m);
      unsigned cand = (tiou == m) ? tinv : 0u;
      cand = dpp_umax<0x128>(cand);
      cand = dpp_umax<0x124>(cand);
      cand = dpp_umax<0x122>(cand);
      cand = dpp_umax<0x121>(cand);
      if ((lane & 15) == 0)
        kq[o][wid * 4 + (lane >> 4)] =
            ((unsigned long long)__float_as_uint(m) << 32) |
            (unsigned long long)cand;
    }
  }

  // ---- losses with UNFORCED (bov,bidx); k_fix corrects forced priors ----
  float vx = 0.f, vy = 0.f, vz = 0.f, vw = 0.f;
  #pragma unroll
  for (int k = 0; k < KC_; ++k) {
    const unsigned p = 0xFFFFFFFFu - pinv[k];
    const size_t bp = (size_t)b * P_ + p;
    const float ov = bov[k];
    const int idx = bidx[k];
    const bool pos = !(ov < THRESH_);
    const bool pos1 = pos && (tlbl[idx] > 0.f);
    float2 cf = reinterpret_cast<const float2*>(conf_data)[bp];
    vy += focal_term(cf, pos);
    if (pos) {
      float4 loc = reinterpret_cast<const float4*>(loc_data)[bp];
      vx += giou_term(pr[k], loc, tsh[idx][0], tsh[idx][1], tsh[idx][2], tsh[idx][3]);
      if (pos1) {
        vw += 1.f;
        vz += landm_term(pr[k], landm_data + bp * 10, &tlm[idx][0]);
      }
    }
  }

  __syncthreads();
  if (tid < O_) {
    unsigned long long best = kq[tid][0];
    #pragma unroll
    for (int s = 1; s < 16; ++s) {
      unsigned long long v = kq[tid][s];
      if (v > best) best = v;
    }
    atomicMax(&ws->gkey[(size_t)b * O_ + tid], best);
  }

  #pragma unroll
  for (int i = 32; i > 0; i >>= 1) {
    vx += __shfl_xor(vx, i);
    vy += __shfl_xor(vy, i);
    vz += __shfl_xor(vz, i);
    vw += __shfl_xor(vw, i);
  }
  if (lane == 0) wsum[wid] = make_float4(vx, vy, vz, vw);
  __syncthreads();
  if (tid == 0) {
    float sx = 0.f, sy = 0.f, sz = 0.f, sw = 0.f;
    #pragma unroll
    for (int w = 0; w < 4; ++w) {
      sx += wsum[w].x; sy += wsum[w].y; sz += wsum[w].z; sw += wsum[w].w;
    }
    ws->part[(size_t)b * GX_ + bx] = make_float4(sx, sy, sz, sw);
  }
}

// ------- forced-match correction (exact mirror of fused semantics) ----------
__global__ __launch_bounds__(64) void k_fix(const float* __restrict__ loc_data,
                                            const float* __restrict__ conf_data,
                                            const float* __restrict__ landm_data,
                                            const float* __restrict__ priors,
                                            const float* __restrict__ targets,
                                            WSHdr* __restrict__ ws) {
  __shared__ float tsh[O_][5];
  __shared__ float tlbl[O_];
  __shared__ float tlm[O_][10];
  const int b = blockIdx.x;
  const int tid = threadIdx.x;
  if (tid < O_) {
    const float* trow = targets + ((size_t)b * O_ + tid) * 15;
    float x1 = trow[0], y1 = trow[1], x2 = trow[2], y2 = trow[3];
    tsh[tid][0] = x1; tsh[tid][1] = y1; tsh[tid][2] = x2; tsh[tid][3] = y2;
    tsh[tid][4] = (x2 - x1) * (y2 - y1);
    #pragma unroll
    for (int k = 0; k < 10; ++k) tlm[tid][k] = trow[4 + k];
    tlbl[tid] = trow[14];
  }
  __syncthreads();

  unsigned fp = 0xFFFFFFFFu;
  if (tid < O_)
    fp = 0xFFFFFFFFu - (unsigned)(ws->gkey[(size_t)b * O_ + tid] & 0xFFFFFFFFull);
  bool alive = tid < O_;
  for (int j2 = 0; j2 < O_; ++j2) {       // last-j-wins dedupe
    unsigned f2 = __shfl(fp, j2, 64);
    if (j2 > tid && f2 == fp) alive = false;
  }

  float dll = 0.f, dlc = 0.f, dllm = 0.f, dn1 = 0.f;
  if (alive) {
    const int p = (int)fp;
    const size_t bp = (size_t)b * P_ + p;
    float4 pr = reinterpret_cast<const float4*>(priors)[p];
    float px1 = pr.x - pr.z * 0.5f, py1 = pr.y - pr.w * 0.5f;
    float px2 = pr.x + pr.z * 0.5f, py2 = pr.y + pr.w * 0.5f;
    float pa = (px2 - px1) * (py2 - py1);
    float bov = 0.f;
    int bidx = 0;
    for (int o = 0; o < O_; ++o) {
      const float x1 = tsh[o][0], y1 = tsh[o][1], x2 = tsh[o][2], y2 = tsh[o][3];
      const float ta = tsh[o][4];
      float iw = fmaxf(fminf(x2, px2) - fmaxf(x1, px1), 0.f);
      float ih = fmaxf(fminf(y2, py2) - fmaxf(y1, py1), 0.f);
      float inter = iw * ih;
      float iou = inter * frcp(ta + pa - inter);
      if (iou > bov) { bov = iou; bidx = o; }
    }
    float2 cf = reinterpret_cast<const float2*>(conf_data)[bp];
    float4 loc = reinterpret_cast<const float4*>(loc_data)[bp];
    const float* lmrow = landm_data + bp * 10;
    {
      const bool pos = !(bov < THRESH_);
      const bool pos1 = pos && (tlbl[bidx] > 0.f);
      dlc -= focal_term(cf, pos);
      if (pos) {
        dll -= giou_term(pr, loc, tsh[bidx][0], tsh[bidx][1], tsh[bidx][2], tsh[bidx][3]);
        if (pos1) {
          dn1 -= 1.f;
          dllm -= landm_term(pr, lmrow, &tlm[bidx][0]);
        }
      }
    }
    {
      const int idx = tid;
      const bool pos1 = tlbl[idx] > 0.f;
      dlc += focal_term(cf, true);
      dll += giou_term(pr, loc, tsh[idx][0], tsh[idx][1], tsh[idx][2], tsh[idx][3]);
      if (pos1) {
        dn1 += 1.f;
        dllm += landm_term(pr, lmrow, &tlm[idx][0]);
      }
    }
  }
  #pragma unroll
  for (int i = 32; i > 0; i >>= 1) {
    dll += __shfl_xor(dll, i);
    dlc += __shfl_xor(dlc, i);
    dllm += __shfl_xor(dllm, i);
    dn1 += __shfl_xor(dn1, i);
  }
  if (tid == 0) {
    ws->corr[b][0] = (double)dll;
    ws->corr[b][1] = (double)dlc;
    ws->corr[b][2] = (double)dllm;
    ws->corr[b][3] = (double)dn1;
  }
}

// ------- final reduction ----------------------------------------------------
__global__ __launch_bounds__(256) void k_final(const WSHdr* __restrict__ ws,
                                               float* __restrict__ out) {
  __shared__ double sh[4][4];
  const int tid = threadIdx.x;
  double sx = 0.0, sy = 0.0, sz = 0.0, sw = 0.0;
  for (int i = tid; i < GX_ * B_; i += 256) {
    float4 v = ws->part[i];
    sx += v.x; sy += v.y; sz += v.z; sw += v.w;
  }
  if (tid < B_) {
    sx += ws->corr[tid][0];
    sy += ws->corr[tid][1];
    sz += ws->corr[tid][2];
    sw += ws->corr[tid][3];
  }
  #pragma unroll
  for (int i = 32; i > 0; i >>= 1) {
    sx += __shfl_xor(sx, i);
    sy += __shfl_xor(sy, i);
    sz += __shfl_xor(sz, i);
    sw += __shfl_xor(sw, i);
  }
  const int wave = tid >> 6, lane = tid & 63;
  if (lane == 0) { sh[wave][0] = sx; sh[wave][1] = sy; sh[wave][2] = sz; sh[wave][3] = sw; }
  __syncthreads();
  if (tid == 0) {
    double ax = 0, ay = 0, az = 0, aw = 0;
    #pragma unroll
    for (int w = 0; w < 4; ++w) { ax += sh[w][0]; ay += sh[w][1]; az += sh[w][2]; aw += sh[w][3]; }
    double n1 = aw < 1.0 ? 1.0 : aw;
    out[0] = (float)(2.0 * ax / n1);
    out[1] = (float)(ay / n1);
    out[2] = (float)(az / n1);
  }
}

extern "C" void kernel_launch(void* const* d_in, const int* in_sizes, int n_in,
                              void* d_out, int out_size, void* d_ws, size_t ws_size,
                              hipStream_t stream) {
  (void)in_sizes; (void)n_in; (void)out_size; (void)ws_size;
  const float* loc     = (const float*)d_in[0];
  const float* conf    = (const float*)d_in[1];
  const float* landm   = (const float*)d_in[2];
  const float* priors  = (const float*)d_in[3];
  const float* targets = (const float*)d_in[4];
  WSHdr* ws = (WSHdr*)d_ws;
  float* out = (float*)d_out;

  hipLaunchKernelGGL(k_hist, dim3(HB_), dim3(256), 0, stream, priors, ws);
  hipLaunchKernelGGL(k_scatter2, dim3(HB_), dim3(256), 0, stream, priors, ws);
  hipLaunchKernelGGL(k_fused2, dim3(GX_ * B_), dim3(256), 0, stream,
                     loc, conf, landm, targets, ws);
  hipLaunchKernelGGL(k_fix, dim3(B_), dim3(64), 0, stream,
                     loc, conf, landm, priors, targets, ws);
  hipLaunchKernelGGL(k_final, dim3(1), dim3(256), 0, stream, ws, out);
}